// Round 2
// baseline (4074.666 us; speedup 1.0000x reference)
//
#include <hip/hip_runtime.h>
#include <hip/hip_bf16.h>

typedef __attribute__((ext_vector_type(8))) short short8;
typedef __attribute__((ext_vector_type(4))) float f32x4;
typedef unsigned short u16;

#define NB   4096
#define TT   200
#define DS   32
#define DA   8
#define HH   128
#define HP   136
#define XP   72
#define BB   8
#define NTHR 256

// packed weight layout (u16 element offsets after 8-elem flag header)
#define PFW   0         // 6 flow mats, transposed [m][col][k] : 6*128*128
#define PFWL  98304     // flow time row (k=128) [m][col]      : 6*128
#define PFB   99072     // flow biases [m][col]                : 6*128
#define PTW   99840     // flow_time_w [l][col]                : 2*128
#define PWIH  100096    // gru Wih [n][k<64 pad from 40]       : 384*64
#define PWHH  124672    // gru Whh [n][k]                      : 384*128
#define PBIH  173824    // 384
#define PBHH  174208    // 384
#define PDW   174592    // dec_W [col][k]                      : 32*128
#define PDB   178688    // 32
#define NPK   178720
#define FSTRIDE 16512   // (H+1)*H source stride per flow layer

#define HIDOFF ((size_t)NB * TT * DS)   // element offset of hid inside d_out

__device__ __forceinline__ float bf2f(u16 u){
  union { unsigned int i; float f; } v; v.i = ((unsigned int)u) << 16; return v.f;
}
__device__ __forceinline__ u16 f2bf(float f){
  __hip_bfloat16 h = __float2bfloat16(f);
  return *reinterpret_cast<u16*>(&h);
}
__device__ __forceinline__ float sigm(float x){
  return __builtin_amdgcn_rcpf(1.f + __expf(-x));
}
__device__ __forceinline__ float tanh_(float x){
  return 1.f - 2.f * __builtin_amdgcn_rcpf(1.f + __expf(2.f * x));
}
__device__ __forceinline__ float scrub(float x){
  return fminf(8.f, fmaxf(-8.f, x));
}
__device__ __forceinline__ short8 ld8(const u16* p){
  return *reinterpret_cast<const short8*>(p);
}
#define MFMA __builtin_amdgcn_mfma_f32_16x16x32_bf16

__global__ void detect_kernel(const void* t_in, int* ws_flag){
  int lane = threadIdx.x;
  u16 v = ((const u16*)t_in)[2 * lane];
  float f = bf2f(v);
  bool ok = (f >= 0.0009765625f) && (f < 1.0f);
  unsigned long long m = __ballot(ok);
  if (lane == 0) ws_flag[0] = (__popcll(m) < 32) ? 1 : 0;   // 1 => fp32
}

__global__ void conv_kernel(const void* Wr, const void* Wz, const void* Wh,
                            const void* br, const void* bz, const void* bh,
                            const void* tw, const void* Wih, const void* Whh,
                            const void* bih, const void* bhh,
                            const void* dW, const void* db_, void* ws){
  const int flag = *(const int*)ws;
  u16* dst = (u16*)ws + 8;
  int i = blockIdx.x * 256 + threadIdx.x;
  if (i >= NPK) return;
  auto cv = [&](const void* p, int li) -> u16 {
    if (flag) return f2bf(((const float*)p)[li]);
    return ((const u16*)p)[li];
  };
  const void* FG[3]  = { Wr, Wz, Wh };
  const void* FBp[3] = { br, bz, bh };
  u16 v;
  if (i < PFWL){ int m = i >> 14, r = i & 16383, col = r >> 7, k = r & 127;
                 int l = m / 3, g = m % 3;
                 v = cv(FG[g], l*FSTRIDE + k*HH + col); }            // transpose
  else if (i < PFB){ int li = i - PFWL; int m = li >> 7, col = li & 127;
                 int l = m / 3, g = m % 3;
                 v = cv(FG[g], l*FSTRIDE + HH*HH + col); }           // k=128 row
  else if (i < PTW){ int li = i - PFB; int m = li >> 7, col = li & 127;
                 int l = m / 3, g = m % 3;
                 v = cv(FBp[g], l*HH + col); }
  else if (i < PWIH){ v = cv(tw, i - PTW); }
  else if (i < PWHH){ int li = i - PWIH; int n = li >> 6, k = li & 63;
                 v = (k < 40) ? cv(Wih, n*40 + k) : (u16)0; }
  else if (i < PBIH){ v = cv(Whh, i - PWHH); }
  else if (i < PBHH){ v = cv(bih, i - PBIH); }
  else if (i < PDW) { v = cv(bhh, i - PBHH); }
  else if (i < PDB) { v = cv(dW,  i - PDW); }
  else              { v = cv(db_, i - PDB); }
  dst[i] = v;
}

__global__ __launch_bounds__(NTHR, 2)
void odernn_kernel(const void* __restrict__ s_in, const void* __restrict__ a_in,
                   const void* __restrict__ t_in, void* __restrict__ out,
                   const void* __restrict__ ws){
  __shared__ alignas(16) u16 h_sh[2][8][HP];
  __shared__ alignas(16) u16 rh_sh[8][HP];
  __shared__ alignas(16) u16 x_sh[8][XP];
  __shared__ float t_sh[8];

  const int flag = *(const int*)ws;
  const u16* pk  = (const u16*)ws + 8;

  const int tid  = threadIdx.x;
  const int w    = tid >> 6;
  const int lane = tid & 63;
  const int q    = lane >> 4;
  const int m16  = lane & 15;
  const bool hi  = (q >= 2);                       // lanes owning column-tile 1
  const int row4 = (q & 1) << 2;                   // merged row base: 0 or 4
  const int colm = (w << 5) + ((q >> 1) << 4) + m16; // merged column 0..127
  const int aoff  = (m16 & 7) * HP + (q << 3);     // A-frag elem offset (+ks*32)
  const int aoffx = (m16 & 7) * XP + (q << 3);
  const int b0   = blockIdx.x * BB;

  for (int i = tid; i < 2*8*HP; i += NTHR) (&h_sh[0][0][0])[i] = 0;
  for (int i = tid; i < 8*XP;   i += NTHR) (&x_sh[0][0])[i]   = 0;
  if (tid < BB){
    size_t idx = (size_t)(b0 + tid) * TT;
    t_sh[tid] = flag ? ((const float*)t_in)[idx] : bf2f(((const u16*)t_in)[idx]);
  }

  // per-lane scalar params at merged column
  float fwl[6], fb[6];
#pragma unroll
  for (int m = 0; m < 6; ++m){
    fwl[m] = bf2f(pk[PFWL + m*HH + colm]);
    fb[m]  = bf2f(pk[PFB  + m*HH + colm]);
  }
  const float ftw0 = bf2f(pk[PTW + colm]);
  const float ftw1 = bf2f(pk[PTW + HH + colm]);
  const float bs_r = bf2f(pk[PBIH + colm])      + bf2f(pk[PBHH + colm]);
  const float bs_z = bf2f(pk[PBIH + HH + colm]) + bf2f(pk[PBHH + HH + colm]);
  const float bi_n = bf2f(pk[PBIH + 2*HH + colm]);
  const float bh_n = bf2f(pk[PBHH + 2*HH + colm]);
  const float db   = bf2f(pk[PDB + ((w & 1) << 4) + m16]);   // used by w<2

  // streamed B-fragment base offsets (element units); two 16-col tiles per wave
  int fB[6][2], whB[3][2], wiB[3][2];
#pragma unroll
  for (int m = 0; m < 6; ++m)
#pragma unroll
    for (int c = 0; c < 2; ++c)
      fB[m][c] = PFW + m*16384 + (((w*2 + c)*16 + m16) << 7) + (q << 3);
#pragma unroll
  for (int g = 0; g < 3; ++g)
#pragma unroll
    for (int c = 0; c < 2; ++c){
      whB[g][c] = PWHH + ((g*HH + (w*2 + c)*16 + m16) << 7) + (q << 3);
      wiB[g][c] = PWIH + ((g*HH + (w*2 + c)*16 + m16) << 6) + (q << 3);
    }
  const int dwB = PDW + (((w & 1)*16 + m16) << 7) + (q << 3);

  // prefetch s/a for t=0
  float sP, aP = 0.f;
  { int row = tid >> 5, c = tid & 31;
    size_t sidx = ((size_t)(b0 + row)*TT + 0)*DS + c;
    sP = flag ? ((const float*)s_in)[sidx] : bf2f(((const u16*)s_in)[sidx]); }
  if (tid < 64){ int row = tid >> 3, c = tid & 7;
    size_t aidx = ((size_t)(b0 + row)*TT + 0)*DA + c;
    aP = flag ? ((const float*)a_in)[aidx] : bf2f(((const u16*)a_in)[aidx]); }

  float hv[4] = {0.f, 0.f, 0.f, 0.f};
  int cur = 0;
  __syncthreads();

  for (int t = 0; t < TT; ++t){
    float tt4[4];
#pragma unroll
    for (int r = 0; r < 4; ++r) tt4[r] = t_sh[row4 + r];

    // decoder for t-1 (overlaps flow), waves 0-1, valid rows in q<2 lanes
    if (w < 2 && t > 0){
      const u16* hr = &h_sh[cur][0][0];
      f32x4 oa = {0.f,0.f,0.f,0.f};
#pragma unroll
      for (int ks = 0; ks < 4; ++ks){
        short8 haf = *reinterpret_cast<const short8*>(hr + aoff + ks*32);
        short8 bw  = ld8(pk + dwB + ks*32);
        oa = MFMA(haf, bw, oa, 0, 0, 0);
      }
      if (q < 2){
#pragma unroll
        for (int r = 0; r < 4; ++r){
          size_t oidx = ((size_t)(b0 + (q<<2) + r)*TT + (t-1))*DS + ((w&1)<<4) + m16;
          float val = oa[r] + db;
          if (flag) ((float*)out)[oidx] = val; else ((u16*)out)[oidx] = f2bf(val);
        }
      }
    }

#pragma unroll
    for (int l = 0; l < 2; ++l){
      const u16* hr = &h_sh[cur][0][0];
      u16* hw = &h_sh[cur ^ 1][0][0];
      short8 ha[4];
#pragma unroll
      for (int ks = 0; ks < 4; ++ks)
        ha[ks] = *reinterpret_cast<const short8*>(hr + aoff + ks*32);
      f32x4 r0={0.f,0.f,0.f,0.f}, r1={0.f,0.f,0.f,0.f};
      f32x4 z0={0.f,0.f,0.f,0.f}, z1={0.f,0.f,0.f,0.f};
#pragma unroll
      for (int ks = 0; ks < 4; ++ks){
        r0 = MFMA(ha[ks], ld8(pk + fB[3*l+0][0] + ks*32), r0, 0,0,0);
        r1 = MFMA(ha[ks], ld8(pk + fB[3*l+0][1] + ks*32), r1, 0,0,0);
        z0 = MFMA(ha[ks], ld8(pk + fB[3*l+1][0] + ks*32), z0, 0,0,0);
        z1 = MFMA(ha[ks], ld8(pk + fB[3*l+1][1] + ks*32), z1, 0,0,0);
      }
      float zv[4];
#pragma unroll
      for (int r = 0; r < 4; ++r){
        // hi lanes (D-rows 8..11 / 12..15) hold exact duplicates of batch
        // rows row4..row4+3 for tile 1 — select own-lane value, no shuffle.
        float ra = hi ? r1[r] : r0[r];
        float za = hi ? z1[r] : z0[r];
        float rv = 0.8f * sigm(ra + tt4[r]*fwl[3*l+0] + fb[3*l+0]);
        zv[r]    = 0.4f * sigm(za + tt4[r]*fwl[3*l+1] + fb[3*l+1]);
        rh_sh[row4 + r][colm] = f2bf(rv * hv[r]);
      }
      if (l == 1){
        { int row = tid >> 5, c = tid & 31; x_sh[row][c] = f2bf(sP); }
        if (tid < 64){ int row = tid >> 3, c = tid & 7; x_sh[row][DS + c] = f2bf(aP); }
        if (t + 1 < TT){   // prefetch next timestep's s/a into registers
          int row = tid >> 5, c = tid & 31;
          size_t sidx = ((size_t)(b0 + row)*TT + (t+1))*DS + c;
          sP = flag ? ((const float*)s_in)[sidx] : bf2f(((const u16*)s_in)[sidx]);
          if (tid < 64){ int r2 = tid >> 3, c2 = tid & 7;
            size_t aidx = ((size_t)(b0 + r2)*TT + (t+1))*DA + c2;
            aP = flag ? ((const float*)a_in)[aidx] : bf2f(((const u16*)a_in)[aidx]); }
        }
      }
      __syncthreads();
      short8 ua[4];
#pragma unroll
      for (int ks = 0; ks < 4; ++ks)
        ua[ks] = *reinterpret_cast<const short8*>(&rh_sh[0][0] + aoff + ks*32);
      f32x4 u0={0.f,0.f,0.f,0.f}, u1={0.f,0.f,0.f,0.f};
#pragma unroll
      for (int ks = 0; ks < 4; ++ks){
        u0 = MFMA(ua[ks], ld8(pk + fB[3*l+2][0] + ks*32), u0, 0,0,0);
        u1 = MFMA(ua[ks], ld8(pk + fB[3*l+2][1] + ks*32), u1, 0,0,0);
      }
      const float ftwl = l ? ftw1 : ftw0;
#pragma unroll
      for (int r = 0; r < 4; ++r){
        float ume = hi ? u1[r] : u0[r];
        float u   = tanh_(ume + tt4[r]*fwl[3*l+2] + fb[3*l+2]);
        float phi = tanh_(ftwl * tt4[r]);
        hv[r] = scrub(hv[r] + phi * zv[r] * (u - hv[r]));
        hw[(row4 + r)*HP + colm] = f2bf(hv[r]);
      }
      __syncthreads();
      cur ^= 1;
    }

    // GRU (hv on entry == post-flow h == `hid` for this timestep)
    {
      const u16* hg = &h_sh[cur][0][0];
      u16* hw = &h_sh[cur ^ 1][0][0];
      short8 xa[2];
#pragma unroll
      for (int ks = 0; ks < 2; ++ks)
        xa[ks] = *reinterpret_cast<const short8*>(&x_sh[0][0] + aoffx + ks*32);
      short8 hgf[4];
#pragma unroll
      for (int ks = 0; ks < 4; ++ks)
        hgf[ks] = *reinterpret_cast<const short8*>(hg + aoff + ks*32);
      f32x4 ar0={0.f,0.f,0.f,0.f}, ar1={0.f,0.f,0.f,0.f};
      f32x4 az0={0.f,0.f,0.f,0.f}, az1={0.f,0.f,0.f,0.f};
      f32x4 an0={0.f,0.f,0.f,0.f}, an1={0.f,0.f,0.f,0.f};
      f32x4 ah0={0.f,0.f,0.f,0.f}, ah1={0.f,0.f,0.f,0.f};
#pragma unroll
      for (int ks = 0; ks < 2; ++ks){
        ar0 = MFMA(xa[ks], ld8(pk + wiB[0][0] + ks*32), ar0, 0,0,0);
        ar1 = MFMA(xa[ks], ld8(pk + wiB[0][1] + ks*32), ar1, 0,0,0);
        az0 = MFMA(xa[ks], ld8(pk + wiB[1][0] + ks*32), az0, 0,0,0);
        az1 = MFMA(xa[ks], ld8(pk + wiB[1][1] + ks*32), az1, 0,0,0);
        an0 = MFMA(xa[ks], ld8(pk + wiB[2][0] + ks*32), an0, 0,0,0);
        an1 = MFMA(xa[ks], ld8(pk + wiB[2][1] + ks*32), an1, 0,0,0);
      }
#pragma unroll
      for (int ks = 0; ks < 4; ++ks){
        ar0 = MFMA(hgf[ks], ld8(pk + whB[0][0] + ks*32), ar0, 0,0,0);
        ar1 = MFMA(hgf[ks], ld8(pk + whB[0][1] + ks*32), ar1, 0,0,0);
        az0 = MFMA(hgf[ks], ld8(pk + whB[1][0] + ks*32), az0, 0,0,0);
        az1 = MFMA(hgf[ks], ld8(pk + whB[1][1] + ks*32), az1, 0,0,0);
        ah0 = MFMA(hgf[ks], ld8(pk + whB[2][0] + ks*32), ah0, 0,0,0);
        ah1 = MFMA(hgf[ks], ld8(pk + whB[2][1] + ks*32), ah1, 0,0,0);
      }
      if (tid < BB && t + 1 < TT){
        size_t idx = (size_t)(b0 + tid)*TT + t + 1;
        t_sh[tid] = flag ? ((const float*)t_in)[idx] : bf2f(((const u16*)t_in)[idx]);
      }
#pragma unroll
      for (int r = 0; r < 4; ++r){
        float arm = hi ? ar1[r] : ar0[r];
        float azm = hi ? az1[r] : az0[r];
        float anm = hi ? an1[r] : an0[r];
        float ahm = hi ? ah1[r] : ah0[r];
        float hpre = hv[r];                       // hid = post-flow, PRE-GRU h
        size_t hidx = HIDOFF + ((size_t)(b0 + row4 + r)*TT + t)*HH + colm;
        if (flag) ((float*)out)[hidx] = hpre; else ((u16*)out)[hidx] = f2bf(hpre);
        float gr = sigm(arm + bs_r);
        float gz = sigm(azm + bs_z);
        float gn = tanh_(anm + bi_n + gr*(ahm + bh_n));
        hv[r] = scrub((1.f - gz)*gn + gz*hpre);
        hw[(row4 + r)*HP + colm] = f2bf(hv[r]);
      }
      __syncthreads();
      cur ^= 1;
    }
  }

  // final decoder (t = TT-1)
  if (w < 2){
    const u16* hr = &h_sh[cur][0][0];
    f32x4 oa = {0.f,0.f,0.f,0.f};
#pragma unroll
    for (int ks = 0; ks < 4; ++ks){
      short8 haf = *reinterpret_cast<const short8*>(hr + aoff + ks*32);
      short8 bw  = ld8(pk + dwB + ks*32);
      oa = MFMA(haf, bw, oa, 0, 0, 0);
    }
    if (q < 2){
#pragma unroll
      for (int r = 0; r < 4; ++r){
        size_t oidx = ((size_t)(b0 + (q<<2) + r)*TT + (TT-1))*DS + ((w&1)<<4) + m16;
        float val = oa[r] + db;
        if (flag) ((float*)out)[oidx] = val; else ((u16*)out)[oidx] = f2bf(val);
      }
    }
  }
}

extern "C" void kernel_launch(void* const* d_in, const int* in_sizes, int n_in,
                              void* d_out, int out_size, void* d_ws, size_t ws_size,
                              hipStream_t stream){
  detect_kernel<<<1, 64, 0, stream>>>(d_in[2], (int*)d_ws);
  conv_kernel<<<(NPK + 255)/256, 256, 0, stream>>>(d_in[3], d_in[5], d_in[7],
                                                   d_in[4], d_in[6], d_in[8],
                                                   d_in[9], d_in[10], d_in[11],
                                                   d_in[12], d_in[13], d_in[14],
                                                   d_in[15], d_ws);
  odernn_kernel<<<dim3(NB/BB), dim3(NTHR), 0, stream>>>(
      d_in[0], d_in[1], d_in[2], d_out, d_ws);
}

// Round 3
// 2411.705 us; speedup vs baseline: 1.6895x; 1.6895x over previous
//
#include <hip/hip_runtime.h>
#include <hip/hip_bf16.h>

typedef __attribute__((ext_vector_type(8))) short short8;
typedef __attribute__((ext_vector_type(4))) float f32x4;
typedef unsigned short u16;

#define NB   4096
#define TT   200
#define DS   32
#define DA   8
#define HH   128
#define HP   136
#define XP   72
#define BB   16
#define GS   8
#define NTHR 512

#define OW_R 0
#define OW_Z 33024
#define OW_H 66048
#define OB_R 99072
#define OB_Z 99328
#define OB_H 99584
#define OTW  99840
#define OWIH 100096
#define OWHH 124672
#define OBIH 173824
#define OBHH 174208
#define ODW  174592
#define ODB  178688
#define NPK  178720
#define OFF2 16512
#define HIDOFF ((size_t)NB * TT * DS)   // element offset of hid inside d_out

__device__ __forceinline__ float bf2f(u16 u){
  union { unsigned int i; float f; } v; v.i = ((unsigned int)u) << 16; return v.f;
}
__device__ __forceinline__ u16 f2bf(float f){
  __hip_bfloat16 h = __float2bfloat16(f);
  return *reinterpret_cast<u16*>(&h);
}
__device__ __forceinline__ float sigm(float x){
  return __builtin_amdgcn_rcpf(1.f + __expf(-x));
}
__device__ __forceinline__ float tanh_(float x){
  return 1.f - 2.f * __builtin_amdgcn_rcpf(1.f + __expf(2.f * x));
}
__device__ __forceinline__ float scrub(float x){
  return fminf(8.f, fmaxf(-8.f, x));
}
__device__ __forceinline__ short8 ld8(const u16* p){
  return *reinterpret_cast<const short8*>(p);
}
#define MFMA __builtin_amdgcn_mfma_f32_16x16x32_bf16

__global__ void detect_kernel(const void* t_in, int* ws_flag){
  int lane = threadIdx.x;
  u16 v = ((const u16*)t_in)[2 * lane];
  float f = bf2f(v);
  bool ok = (f >= 0.0009765625f) && (f < 1.0f);
  unsigned long long m = __ballot(ok);
  if (lane == 0) ws_flag[0] = (__popcll(m) < 32) ? 1 : 0;   // 1 => fp32
}

__global__ void conv_kernel(const void* Wr, const void* Wz, const void* Wh,
                            const void* br, const void* bz, const void* bh,
                            const void* tw, const void* Wih, const void* Whh,
                            const void* bih, const void* bhh,
                            const void* dW, const void* db_, void* ws){
  const int flag = *(const int*)ws;
  u16* dst = (u16*)ws + 8;
  int i = blockIdx.x * 256 + threadIdx.x;
  if (i >= NPK) return;
  auto cv = [&](const void* p, int li) -> u16 {
    if (flag) return f2bf(((const float*)p)[li]);
    return ((const u16*)p)[li];
  };
  u16 v;
  if      (i < OW_Z) v = cv(Wr,  i - OW_R);
  else if (i < OW_H) v = cv(Wz,  i - OW_Z);
  else if (i < OB_R) v = cv(Wh,  i - OW_H);
  else if (i < OB_Z) v = cv(br,  i - OB_R);
  else if (i < OB_H) v = cv(bz,  i - OB_Z);
  else if (i < OTW)  v = cv(bh,  i - OB_H);
  else if (i < OWIH) v = cv(tw,  i - OTW);
  else if (i < OWHH) { int li = i - OWIH; int n = li >> 6, k = li & 63;
                       v = (k < 40) ? cv(Wih, n * 40 + k) : (u16)0; }
  else if (i < OBIH) v = cv(Whh, i - OWHH);
  else if (i < OBHH) v = cv(bih, i - OBIH);
  else if (i < ODW)  v = cv(bhh, i - OBHH);
  else if (i < ODB)  v = cv(dW,  i - ODW);
  else               v = cv(db_, i - ODB);
  dst[i] = v;
}

__global__ __launch_bounds__(NTHR, 2)
void odernn_kernel(const void* __restrict__ s_in, const void* __restrict__ a_in,
                   const void* __restrict__ t_in, void* __restrict__ out,
                   const void* __restrict__ ws){
  // [buf][group][row(8)][col(pad)]
  __shared__ alignas(16) u16 h_sh[2][2][GS][HP];
  __shared__ alignas(16) u16 rh_sh[2][GS][HP];
  __shared__ alignas(16) u16 x_sh[2][GS][XP];
  __shared__ float t_sh[BB];

  const int flag = *(const int*)ws;
  const u16* pk  = (const u16*)ws + 8;

  const int tid  = threadIdx.x;
  const int w    = tid >> 6;
  const int lane = tid & 63;
  const int q    = lane >> 4;
  const int m16  = lane & 15;
  const int col  = (w << 4) | m16;            // 0..127, this lane's H column
  const bool hiq = (q >= 2);                  // lanes taking acc elems {2,3}
  const int rowL = ((q & 1) << 2) | ((q >> 1) << 1); // 0,4,2,6 — 2 rows each
  const int aoff  = (m16 & 7) * HP + (q << 3); // A-frag base (8-row aliased)
  const int aoffx = (m16 & 7) * XP + (q << 3);
  const int b0   = blockIdx.x * BB;

  for (int i = tid; i < 2*2*GS*HP; i += NTHR) (&h_sh[0][0][0][0])[i] = 0;
  for (int i = tid; i < 2*GS*XP;   i += NTHR) (&x_sh[0][0][0])[i]   = 0;
  if (tid < BB){
    size_t idx = (size_t)(b0 + tid) * TT;
    t_sh[tid] = flag ? ((const float*)t_in)[idx] : bf2f(((const u16*)t_in)[idx]);
  }

  // persistent weight fragments (identical to the 913us baseline)
  const u16* WrP = pk + OW_R; const u16* WzP = pk + OW_Z; const u16* WhP = pk + OW_H;
  const u16* Wsrc[6] = { WrP, WzP, WhP, WrP + OFF2, WzP + OFF2, WhP + OFF2 };
  short8 fw[6][4];
  float fwl[6], fb[6];
#pragma unroll
  for (int m = 0; m < 6; ++m){
#pragma unroll
    for (int ks = 0; ks < 4; ++ks){
      short8 v;
#pragma unroll
      for (int j = 0; j < 8; ++j)
        v[j] = (short)Wsrc[m][(ks*32 + q*8 + j)*HH + col];
      fw[m][ks] = v;
    }
    fwl[m] = bf2f(Wsrc[m][128*HH + col]);
  }
  fb[0] = bf2f(pk[OB_R + col]);      fb[1] = bf2f(pk[OB_Z + col]);      fb[2] = bf2f(pk[OB_H + col]);
  fb[3] = bf2f(pk[OB_R + HH + col]); fb[4] = bf2f(pk[OB_Z + HH + col]); fb[5] = bf2f(pk[OB_H + HH + col]);
  const float ftw0 = bf2f(pk[OTW + col]), ftw1 = bf2f(pk[OTW + HH + col]);

  short8 whhf[3][4];
#pragma unroll
  for (int g = 0; g < 3; ++g){
    const u16* base = pk + OWHH + (size_t)(g*HH + col) * HH;
#pragma unroll
    for (int ks = 0; ks < 4; ++ks)
      whhf[g][ks] = *reinterpret_cast<const short8*>(base + ks*32 + q*8);
  }
  const float bs_r = bf2f(pk[OBIH + col])      + bf2f(pk[OBHH + col]);
  const float bs_z = bf2f(pk[OBIH + HH + col]) + bf2f(pk[OBHH + HH + col]);
  const float bi_n = bf2f(pk[OBIH + 2*HH + col]);
  const float bh_n = bf2f(pk[OBHH + 2*HH + col]);
  const float db   = bf2f(pk[ODB + (col & 31)]);

  // prefetch s/a for t=0 (16 rows)
  float sP, aP = 0.f;
  { int row = tid >> 5, c = tid & 31;
    size_t sidx = (size_t)(b0 + row)*TT*DS + c;
    sP = flag ? ((const float*)s_in)[sidx] : bf2f(((const u16*)s_in)[sidx]); }
  if (tid < BB*DA){ int row = tid >> 3, c = tid & 7;
    size_t aidx = (size_t)(b0 + row)*TT*DA + c;
    aP = flag ? ((const float*)a_in)[aidx] : bf2f(((const u16*)a_in)[aidx]); }

  float hv[2][2] = {{0.f,0.f},{0.f,0.f}};   // [group][r] — this lane's 2 rows
  int cur = 0;
  __syncthreads();

  for (int t = 0; t < TT; ++t){
    float tt[2][2];
#pragma unroll
    for (int g = 0; g < 2; ++g)
#pragma unroll
      for (int r = 0; r < 2; ++r) tt[g][r] = t_sh[g*GS + rowL + r];

    // decoder for t-1 (overlaps flow): waves 0,1 -> group0; 2,3 -> group1
    if (w < 4 && t > 0){
      const u16* hr = &h_sh[cur][w >> 1][0][0];
      f32x4 oa = {0.f,0.f,0.f,0.f};
#pragma unroll
      for (int ks = 0; ks < 4; ++ks){
        short8 haf = ld8(hr + aoff + ks*32);
        short8 bw  = ld8(pk + ODW + (col & 31)*HH + ks*32 + q*8);
        oa = MFMA(haf, bw, oa, 0, 0, 0);
      }
#pragma unroll
      for (int r = 0; r < 2; ++r){
        float val = (hiq ? oa[2+r] : oa[r]) + db;
        size_t oidx = ((size_t)(b0 + (w>>1)*GS + rowL + r)*TT + (t-1))*DS + (col & 31);
        if (flag) ((float*)out)[oidx] = val; else ((u16*)out)[oidx] = f2bf(val);
      }
    }

#pragma unroll
    for (int l = 0; l < 2; ++l){
      short8 ha[2][4];
#pragma unroll
      for (int g = 0; g < 2; ++g)
#pragma unroll
        for (int ks = 0; ks < 4; ++ks)
          ha[g][ks] = ld8(&h_sh[cur][g][0][0] + aoff + ks*32);
      f32x4 rA[2] = {{0.f,0.f,0.f,0.f},{0.f,0.f,0.f,0.f}};
      f32x4 zA[2] = {{0.f,0.f,0.f,0.f},{0.f,0.f,0.f,0.f}};
#pragma unroll
      for (int g = 0; g < 2; ++g)
#pragma unroll
        for (int ks = 0; ks < 4; ++ks){
          rA[g] = MFMA(ha[g][ks], fw[3*l+0][ks], rA[g], 0,0,0);
          zA[g] = MFMA(ha[g][ks], fw[3*l+1][ks], zA[g], 0,0,0);
        }
      float zv[2][2];
#pragma unroll
      for (int g = 0; g < 2; ++g)
#pragma unroll
        for (int r = 0; r < 2; ++r){
          float rm = hiq ? rA[g][2+r] : rA[g][r];
          float zm = hiq ? zA[g][2+r] : zA[g][r];
          float rv = 0.8f * sigm(rm + tt[g][r]*fwl[3*l+0] + fb[3*l+0]);
          zv[g][r] = 0.4f * sigm(zm + tt[g][r]*fwl[3*l+1] + fb[3*l+1]);
          rh_sh[g][rowL + r][col] = f2bf(rv * hv[g][r]);
        }
      if (l == 1){
        { int row = tid >> 5, c = tid & 31; x_sh[row>>3][row&7][c] = f2bf(sP); }
        if (tid < BB*DA){ int row = tid >> 3, c = tid & 7; x_sh[row>>3][row&7][DS + c] = f2bf(aP); }
        if (t + 1 < TT){   // prefetch next timestep's s/a into registers
          int row = tid >> 5, c = tid & 31;
          size_t sidx = ((size_t)(b0 + row)*TT + (t+1))*DS + c;
          sP = flag ? ((const float*)s_in)[sidx] : bf2f(((const u16*)s_in)[sidx]);
          if (tid < BB*DA){ int r2 = tid >> 3, c2 = tid & 7;
            size_t aidx = ((size_t)(b0 + r2)*TT + (t+1))*DA + c2;
            aP = flag ? ((const float*)a_in)[aidx] : bf2f(((const u16*)a_in)[aidx]); }
        }
      }
      __syncthreads();
      short8 ua[2][4];
#pragma unroll
      for (int g = 0; g < 2; ++g)
#pragma unroll
        for (int ks = 0; ks < 4; ++ks)
          ua[g][ks] = ld8(&rh_sh[g][0][0] + aoff + ks*32);
      f32x4 uA[2] = {{0.f,0.f,0.f,0.f},{0.f,0.f,0.f,0.f}};
#pragma unroll
      for (int g = 0; g < 2; ++g)
#pragma unroll
        for (int ks = 0; ks < 4; ++ks)
          uA[g] = MFMA(ua[g][ks], fw[3*l+2][ks], uA[g], 0,0,0);
      const float ftwl = l ? ftw1 : ftw0;
#pragma unroll
      for (int g = 0; g < 2; ++g)
#pragma unroll
        for (int r = 0; r < 2; ++r){
          float um  = hiq ? uA[g][2+r] : uA[g][r];
          float u   = tanh_(um + tt[g][r]*fwl[3*l+2] + fb[3*l+2]);
          float phi = tanh_(ftwl * tt[g][r]);
          hv[g][r] = scrub(hv[g][r] + phi * zv[g][r] * (u - hv[g][r]));
          h_sh[cur ^ 1][g][rowL + r][col] = f2bf(hv[g][r]);
        }
      __syncthreads();
      cur ^= 1;
    }

    // GRU (hv on entry == post-flow h == `hid` for this timestep)
    {
      short8 wihf[3][2];
#pragma unroll
      for (int gg = 0; gg < 3; ++gg)
#pragma unroll
        for (int ks = 0; ks < 2; ++ks)
          wihf[gg][ks] = ld8(pk + OWIH + (size_t)(gg*HH + col)*64 + ks*32 + q*8);
      short8 xa[2][2];
#pragma unroll
      for (int g = 0; g < 2; ++g)
#pragma unroll
        for (int ks = 0; ks < 2; ++ks)
          xa[g][ks] = ld8(&x_sh[g][0][0] + aoffx + ks*32);
      short8 hgf[2][4];
#pragma unroll
      for (int g = 0; g < 2; ++g)
#pragma unroll
        for (int ks = 0; ks < 4; ++ks)
          hgf[g][ks] = ld8(&h_sh[cur][g][0][0] + aoff + ks*32);
      f32x4 ar[2] = {{0.f,0.f,0.f,0.f},{0.f,0.f,0.f,0.f}};
      f32x4 az[2] = {{0.f,0.f,0.f,0.f},{0.f,0.f,0.f,0.f}};
      f32x4 an[2] = {{0.f,0.f,0.f,0.f},{0.f,0.f,0.f,0.f}};
      f32x4 ah[2] = {{0.f,0.f,0.f,0.f},{0.f,0.f,0.f,0.f}};
#pragma unroll
      for (int g = 0; g < 2; ++g)
#pragma unroll
        for (int ks = 0; ks < 2; ++ks){
          ar[g] = MFMA(xa[g][ks], wihf[0][ks], ar[g], 0,0,0);
          az[g] = MFMA(xa[g][ks], wihf[1][ks], az[g], 0,0,0);
          an[g] = MFMA(xa[g][ks], wihf[2][ks], an[g], 0,0,0);
        }
#pragma unroll
      for (int g = 0; g < 2; ++g)
#pragma unroll
        for (int ks = 0; ks < 4; ++ks){
          ar[g] = MFMA(hgf[g][ks], whhf[0][ks], ar[g], 0,0,0);
          az[g] = MFMA(hgf[g][ks], whhf[1][ks], az[g], 0,0,0);
          ah[g] = MFMA(hgf[g][ks], whhf[2][ks], ah[g], 0,0,0);
        }
      if (tid < BB && t + 1 < TT){
        size_t idx = (size_t)(b0 + tid)*TT + t + 1;
        t_sh[tid] = flag ? ((const float*)t_in)[idx] : bf2f(((const u16*)t_in)[idx]);
      }
#pragma unroll
      for (int g = 0; g < 2; ++g)
#pragma unroll
        for (int r = 0; r < 2; ++r){
          float arm = hiq ? ar[g][2+r] : ar[g][r];
          float azm = hiq ? az[g][2+r] : az[g][r];
          float anm = hiq ? an[g][2+r] : an[g][r];
          float ahm = hiq ? ah[g][2+r] : ah[g][r];
          float hpre = hv[g][r];                  // hid = post-flow, PRE-GRU h
          size_t hidx = HIDOFF + ((size_t)(b0 + g*GS + rowL + r)*TT + t)*HH + col;
          if (flag) ((float*)out)[hidx] = hpre; else ((u16*)out)[hidx] = f2bf(hpre);
          float gr = sigm(arm + bs_r);
          float gz = sigm(azm + bs_z);
          float gn = tanh_(anm + bi_n + gr*(ahm + bh_n));
          hv[g][r] = scrub((1.f - gz)*gn + gz*hpre);
          h_sh[cur ^ 1][g][rowL + r][col] = f2bf(hv[g][r]);
        }
      __syncthreads();
      cur ^= 1;
    }
  }

  // final decoder (t = TT-1)
  if (w < 4){
    const u16* hr = &h_sh[cur][w >> 1][0][0];
    f32x4 oa = {0.f,0.f,0.f,0.f};
#pragma unroll
    for (int ks = 0; ks < 4; ++ks){
      short8 haf = ld8(hr + aoff + ks*32);
      short8 bw  = ld8(pk + ODW + (col & 31)*HH + ks*32 + q*8);
      oa = MFMA(haf, bw, oa, 0, 0, 0);
    }
#pragma unroll
    for (int r = 0; r < 2; ++r){
      float val = (hiq ? oa[2+r] : oa[r]) + db;
      size_t oidx = ((size_t)(b0 + (w>>1)*GS + rowL + r)*TT + (TT-1))*DS + (col & 31);
      if (flag) ((float*)out)[oidx] = val; else ((u16*)out)[oidx] = f2bf(val);
    }
  }
}

extern "C" void kernel_launch(void* const* d_in, const int* in_sizes, int n_in,
                              void* d_out, int out_size, void* d_ws, size_t ws_size,
                              hipStream_t stream){
  detect_kernel<<<1, 64, 0, stream>>>(d_in[2], (int*)d_ws);
  conv_kernel<<<(NPK + 255)/256, 256, 0, stream>>>(d_in[3], d_in[5], d_in[7],
                                                   d_in[4], d_in[6], d_in[8],
                                                   d_in[9], d_in[10], d_in[11],
                                                   d_in[12], d_in[13], d_in[14],
                                                   d_in[15], d_ws);
  odernn_kernel<<<dim3(NB/BB), dim3(NTHR), 0, stream>>>(
      d_in[0], d_in[1], d_in[2], d_out, d_ws);
}